// Round 11
// baseline (228.322 us; speedup 1.0000x reference)
//
#include <hip/hip_runtime.h>

#define NF 64
#define OCAP 65536

// ---------------- single-pass ELL build (ELL inside d_out), XCD-windowed ----------------
__global__ __launch_bounds__(256) void k_ell(const int* __restrict__ src,
                                             const int* __restrict__ dst,
                                             int* degc, int* ocnt, int* oflow,
                                             int* ell, int e, int n) {
    int grp = blockIdx.x & 7;
    int chunk = (n + 7) >> 3;
    int lo = grp * chunk;
    int hi = min(lo + chunk, n);
    int nb = gridDim.x >> 3;
    int bi = blockIdx.x >> 3;
    for (int i = bi * 256 + threadIdx.x; i < e; i += nb * 256) {
        int d = dst[i];
        if (d < lo || d >= hi) continue;
        int s = src[i];
        int slot = atomicAdd(&degc[d], 1);
        if (slot < NF) {
            ell[(unsigned)d * NF + slot] = s;
        } else {                                   // P(deg>64)~0; correctness fallback
            int o = atomicAdd(ocnt, 1);
            if (o < OCAP) { oflow[2 * o] = s; oflow[2 * o + 1] = d; }
        }
    }
}

__global__ __launch_bounds__(256) void k_dinv(const int* __restrict__ degc,
                                              float* __restrict__ dinv, int n) {
    int i = blockIdx.x * 256 + threadIdx.x;
    if (i < n) dinv[i] = rsqrtf((float)(degc[i] + 1));   // +1 self-loop
}

// ---------------- phase 1: pure gather-aggregate ----------------
// 1 node/wave, lane = feature. R9's proven loop: 8 x-row + 8 dinv loads in
// flight (MLP=16). No LDS, no barrier. v overwrites the node's own ELL row
// in d_out (read-then-write by the same wave).

__global__ __launch_bounds__(256) void k_agg(const float* __restrict__ x,
                                             const float* __restrict__ dinv,
                                             const int* __restrict__ degc,
                                             float* out, int n) {
    int wv = threadIdx.x >> 6;
    unsigned lane = threadIdx.x & 63;
    const int* outi = (const int*)out;   // ELL aliased in out
    int ngroups = (n + 3) >> 2, gs = gridDim.x;
    int g = blockIdx.x;
    int d = g * 4 + wv;
    int ev = 0, mc = 0;
    if (d < n) {
        ev = outi[(unsigned)d * NF + lane];    // full-wave 256B ELL row
        mc = degc[d];
    }
    while (g < ngroups) {
        int gn = g + gs, dn = gn * 4 + wv;
        int evn = 0, mcn = 0;
        if (gn < ngroups && dn < n) {          // prefetch next iteration
            evn = outi[(unsigned)dn * NF + lane];
            mcn = degc[dn];
        }
        if (d < n) {
            float dd = rsqrtf((float)(mc + 1));
            int m = min(mc, NF);
            float a0 = x[(unsigned)d * NF + lane] * dd;    // self term
            float a1 = 0.f, a2 = 0.f, a3 = 0.f, a4 = 0.f, a5 = 0.f, a6 = 0.f, a7 = 0.f;
            for (int j = 0; j < m; j += 8) {   // 8 x-rows + 8 dinv lines in flight
                int s0 = __shfl(ev, j + 0), s1 = __shfl(ev, j + 1);
                int s2 = __shfl(ev, j + 2), s3 = __shfl(ev, j + 3);
                int s4 = __shfl(ev, j + 4), s5 = __shfl(ev, j + 5);
                int s6 = __shfl(ev, j + 6), s7 = __shfl(ev, j + 7);
                bool b0 = j + 0 < m, b1 = j + 1 < m, b2 = j + 2 < m, b3 = j + 3 < m;
                bool b4 = j + 4 < m, b5 = j + 5 < m, b6 = j + 6 < m, b7 = j + 7 < m;
                s0 = b0 ? s0 : 0; s1 = b1 ? s1 : 0; s2 = b2 ? s2 : 0; s3 = b3 ? s3 : 0;
                s4 = b4 ? s4 : 0; s5 = b5 ? s5 : 0; s6 = b6 ? s6 : 0; s7 = b7 ? s7 : 0;
                float w0 = b0 ? dinv[s0] : 0.f, w1 = b1 ? dinv[s1] : 0.f;
                float w2 = b2 ? dinv[s2] : 0.f, w3 = b3 ? dinv[s3] : 0.f;
                float w4 = b4 ? dinv[s4] : 0.f, w5 = b5 ? dinv[s5] : 0.f;
                float w6 = b6 ? dinv[s6] : 0.f, w7 = b7 ? dinv[s7] : 0.f;
                a0 = fmaf(x[(unsigned)s0 * NF + lane], w0, a0);
                a1 = fmaf(x[(unsigned)s1 * NF + lane], w1, a1);
                a2 = fmaf(x[(unsigned)s2 * NF + lane], w2, a2);
                a3 = fmaf(x[(unsigned)s3 * NF + lane], w3, a3);
                a4 = fmaf(x[(unsigned)s4 * NF + lane], w4, a4);
                a5 = fmaf(x[(unsigned)s5 * NF + lane], w5, a5);
                a6 = fmaf(x[(unsigned)s6 * NF + lane], w6, a6);
                a7 = fmaf(x[(unsigned)s7 * NF + lane], w7, a7);
            }
            float v = dd * (((a0 + a1) + (a2 + a3)) + ((a4 + a5) + (a6 + a7)));
            out[(unsigned)d * NF + lane] = v;  // overwrite own ELL row
        }
        g = gn; d = dn; ev = evn; mc = mcn;
    }
}

// ---------------- phase 2: dense in-place GEMM out = out @ W^T + bias ----------------
// 16 rows/block, 4 rows/wave: each full-wave wt LDS read feeds 4 rows' FMAs.
// vsh exchange is wave-local -> single barrier (wt staging) per kernel.

__global__ __launch_bounds__(256) void k_gemm(const float* __restrict__ W,
                                              const float* __restrict__ bias,
                                              float* out, int n) {
    __shared__ float wt[NF * NF];      // wt[k*64+j] = W[j][k]
    __shared__ float vsh[4][4][NF];
    int tid = threadIdx.x;
    for (int idx = tid; idx < NF * NF; idx += 256) {
        int k = idx >> 6, j = idx & 63;
        wt[idx] = W[j * NF + k];
    }
    int wv = tid >> 6;
    unsigned lane = tid & 63;
    float bj = bias[lane];
    __syncthreads();                   // wt staged (only barrier)

    int ntiles = (n + 15) >> 4, gs = gridDim.x;
    for (int t = blockIdx.x; t < ntiles; t += gs) {
        int r = t * 16 + wv * 4;
        float v0 = (r + 0 < n) ? out[(unsigned)(r + 0) * NF + lane] : 0.f;
        float v1 = (r + 1 < n) ? out[(unsigned)(r + 1) * NF + lane] : 0.f;
        float v2 = (r + 2 < n) ? out[(unsigned)(r + 2) * NF + lane] : 0.f;
        float v3 = (r + 3 < n) ? out[(unsigned)(r + 3) * NF + lane] : 0.f;
        vsh[wv][0][lane] = v0;         // wave-local, no barrier
        vsh[wv][1][lane] = v1;
        vsh[wv][2][lane] = v2;
        vsh[wv][3][lane] = v3;
        float r0 = bj, r1 = bj, r2 = bj, r3 = bj;
#pragma unroll
        for (int k0 = 0; k0 < NF; k0 += 4) {
            float4 b0 = *reinterpret_cast<const float4*>(&vsh[wv][0][k0]);  // broadcast
            float4 b1 = *reinterpret_cast<const float4*>(&vsh[wv][1][k0]);
            float4 b2 = *reinterpret_cast<const float4*>(&vsh[wv][2][k0]);
            float4 b3 = *reinterpret_cast<const float4*>(&vsh[wv][3][k0]);
            float q0 = wt[(k0 + 0) * NF + lane];   // shared across 4 rows
            float q1 = wt[(k0 + 1) * NF + lane];
            float q2 = wt[(k0 + 2) * NF + lane];
            float q3 = wt[(k0 + 3) * NF + lane];
            r0 = fmaf(b0.x, q0, r0); r0 = fmaf(b0.y, q1, r0); r0 = fmaf(b0.z, q2, r0); r0 = fmaf(b0.w, q3, r0);
            r1 = fmaf(b1.x, q0, r1); r1 = fmaf(b1.y, q1, r1); r1 = fmaf(b1.z, q2, r1); r1 = fmaf(b1.w, q3, r1);
            r2 = fmaf(b2.x, q0, r2); r2 = fmaf(b2.y, q1, r2); r2 = fmaf(b2.z, q2, r2); r2 = fmaf(b2.w, q3, r2);
            r3 = fmaf(b3.x, q0, r3); r3 = fmaf(b3.y, q1, r3); r3 = fmaf(b3.z, q2, r3); r3 = fmaf(b3.w, q3, r3);
        }
        if (r + 0 < n) out[(unsigned)(r + 0) * NF + lane] = r0;
        if (r + 1 < n) out[(unsigned)(r + 1) * NF + lane] = r1;
        if (r + 2 < n) out[(unsigned)(r + 2) * NF + lane] = r2;
        if (r + 3 < n) out[(unsigned)(r + 3) * NF + lane] = r3;
    }
}

// ---------------- overflow fixup (post-GEMM, by linearity) ----------------
__global__ __launch_bounds__(64) void k_oflow(const float* __restrict__ x,
                                              const float* __restrict__ W,
                                              const float* __restrict__ dinv,
                                              const int* __restrict__ ocnt,
                                              const int* __restrict__ oflow,
                                              float* out) {
    int c = *ocnt; if (c > OCAP) c = OCAP;
    int lane = threadIdx.x;
    for (int o = blockIdx.x; o < c; o += gridDim.x) {
        int s = oflow[2 * o], d = oflow[2 * o + 1];
        float norm = dinv[s] * dinv[d];
        float r = 0.f;
        for (int k = 0; k < NF; ++k)
            r = fmaf(x[(long)s * NF + k], W[lane * NF + k], r);
        atomicAdd(&out[(long)d * NF + lane], norm * r);
    }
}

// ---------------- launch ----------------

extern "C" void kernel_launch(void* const* d_in, const int* in_sizes, int n_in,
                              void* d_out, int out_size, void* d_ws, size_t ws_size,
                              hipStream_t stream) {
    const float* x    = (const float*)d_in[0];
    const int*   ei   = (const int*)d_in[1];   // harness pushes integers as int32
    const float* W    = (const float*)d_in[2];
    const float* bias = (const float*)d_in[3];
    float*       out  = (float*)d_out;

    const int n = in_sizes[0] / NF;       // 100000
    const int e = in_sizes[1] / 2;        // 1250000
    const int* src = ei;
    const int* dst = ei + e;

    // ws layout (~1.3MB): degc n | ocnt 1 | dinv n | oflow 2*OCAP
    int*   degc  = (int*)d_ws;
    int*   ocnt  = degc + n;
    float* dinv  = (float*)(ocnt + 1);
    int*   oflow = (int*)(dinv + n);

    dim3 blk(256);
    hipMemsetAsync(degc, 0, (size_t)(n + 1) * sizeof(int), stream);  // degc + ocnt
    k_ell <<<2048, blk, 0, stream>>>(src, dst, degc, ocnt, oflow, (int*)out, e, n);
    k_dinv<<<(n + 255) / 256, blk, 0, stream>>>(degc, dinv, n);
    k_agg <<<2048, blk, 0, stream>>>(x, dinv, degc, out, n);
    k_gemm<<<(n + 15) / 16, blk, 0, stream>>>(W, bias, out, n);
    k_oflow<<<64, 64, 0, stream>>>(x, W, dinv, ocnt, oflow, out);
}

// Round 12
// 150.390 us; speedup vs baseline: 1.5182x; 1.5182x over previous
//
#include <hip/hip_runtime.h>
#include <stdint.h>

#define NF 64

// ---------------- single-pass ELL build (ELL inside d_out), XCD-windowed ----------------
// out row d (64 floats) = node d's 64 int slots. Group blockIdx%8 handles only
// dst window g -> all writes to a line come from one XCD's L2, written back once.

__global__ __launch_bounds__(256) void k_ell(const int* __restrict__ src,
                                             const int* __restrict__ dst,
                                             int* degc, int* ocnt, int* oflow, int ocap,
                                             int* ell, int e, int n) {
    int grp = blockIdx.x & 7;
    int chunk = (n + 7) >> 3;
    int lo = grp * chunk;
    int hi = min(lo + chunk, n);
    int nb = gridDim.x >> 3;
    int bi = blockIdx.x >> 3;
    for (int i = bi * 256 + threadIdx.x; i < e; i += nb * 256) {
        int d = dst[i];
        if (d < lo || d >= hi) continue;
        int s = src[i];
        int slot = atomicAdd(&degc[d], 1);
        if (slot < NF) {
            ell[(unsigned)d * NF + slot] = s;
        } else {                                   // P(deg>64)~0; correctness fallback
            int o = atomicAdd(ocnt, 1);
            if (o < ocap) { oflow[2 * o] = s; oflow[2 * o + 1] = d; }
        }
    }
}

// ---------------- prescale: xs[row] = x[row] * rsqrt(deg+1); row n = zeros ----------------
__global__ __launch_bounds__(256) void k_scale(const float* __restrict__ x,
                                               const int* __restrict__ degc,
                                               float* __restrict__ xs, int n) {
    int i = blockIdx.x * 256 + threadIdx.x;      // float4 index
    int total = (n + 1) * (NF / 4);
    if (i >= total) return;
    int row = i >> 4;
    float4 v = {0.f, 0.f, 0.f, 0.f};
    if (row < n) {
        float dd = rsqrtf((float)(degc[row] + 1));
        v = reinterpret_cast<const float4*>(x)[i];
        v.x *= dd; v.y *= dd; v.z *= dd; v.w *= dd;
    }
    reinterpret_cast<float4*>(xs)[i] = v;        // row n -> zero row
}

// ---------------- fused gather-aggregate + GEMM epilogue ----------------
// 1 node/wave, lane = feature. Inner loop: 1 VMEM per edge (prescaled xs),
// invalid slots -> zero row n (unconditional add). 8 independent row chains.
// No in-loop barriers (vsh wave-local). out row overwritten by same wave.

__global__ __launch_bounds__(256) void k_agg_gemm(const float* __restrict__ xs,
                                                  const float* __restrict__ W,
                                                  const float* __restrict__ bias,
                                                  const int* __restrict__ degc,
                                                  float* out, int n) {
    __shared__ float wt[NF * NF];      // wt[k*64+j] = W[j][k]
    __shared__ float vsh[4][NF];
    int tid = threadIdx.x;
    for (int idx = tid; idx < NF * NF; idx += 256) {
        int k = idx >> 6, j = idx & 63;
        wt[idx] = W[j * NF + k];
    }
    int wv = tid >> 6;
    unsigned lane = tid & 63;
    float bj = bias[lane];
    __syncthreads();                   // wt staged (only barrier)

    const int* outi = (const int*)out;   // ELL aliased in out
    int ngroups = (n + 3) >> 2, gs = gridDim.x;
    int g = blockIdx.x;
    int d = g * 4 + wv;
    int ev = 0, mc = 0;
    if (d < n) {
        ev = outi[(unsigned)d * NF + lane];    // full-wave 256B ELL row
        mc = degc[d];
    }
    while (g < ngroups) {
        int gn = g + gs, dn = gn * 4 + wv;
        int evn = 0, mcn = 0;
        if (gn < ngroups && dn < n) {          // prefetch next iteration
            evn = outi[(unsigned)dn * NF + lane];
            mcn = degc[dn];
        }
        if (d < n) {
            float dd = rsqrtf((float)(mc + 1));
            int m = min(mc, NF);
            float a0 = xs[(unsigned)d * NF + lane];    // self term (prescaled)
            float a1 = 0.f, a2 = 0.f, a3 = 0.f, a4 = 0.f, a5 = 0.f, a6 = 0.f, a7 = 0.f;
            for (int j = 0; j < m; j += 8) {   // 8 xs-rows in flight, 1 VMEM/edge
                int s0 = __shfl(ev, j + 0), s1 = __shfl(ev, j + 1);
                int s2 = __shfl(ev, j + 2), s3 = __shfl(ev, j + 3);
                int s4 = __shfl(ev, j + 4), s5 = __shfl(ev, j + 5);
                int s6 = __shfl(ev, j + 6), s7 = __shfl(ev, j + 7);
                s0 = (j + 0 < m) ? s0 : n;     // invalid -> zero row
                s1 = (j + 1 < m) ? s1 : n;
                s2 = (j + 2 < m) ? s2 : n;
                s3 = (j + 3 < m) ? s3 : n;
                s4 = (j + 4 < m) ? s4 : n;
                s5 = (j + 5 < m) ? s5 : n;
                s6 = (j + 6 < m) ? s6 : n;
                s7 = (j + 7 < m) ? s7 : n;
                a0 += xs[(unsigned)s0 * NF + lane];
                a1 += xs[(unsigned)s1 * NF + lane];
                a2 += xs[(unsigned)s2 * NF + lane];
                a3 += xs[(unsigned)s3 * NF + lane];
                a4 += xs[(unsigned)s4 * NF + lane];
                a5 += xs[(unsigned)s5 * NF + lane];
                a6 += xs[(unsigned)s6 * NF + lane];
                a7 += xs[(unsigned)s7 * NF + lane];
            }
            float v = dd * (((a0 + a1) + (a2 + a3)) + ((a4 + a5) + (a6 + a7)));

            vsh[wv][lane] = v;                 // wave-local exchange, no barrier
            float r = bj;
#pragma unroll
            for (int k0 = 0; k0 < NF; k0 += 4) {
                float4 bv = *reinterpret_cast<const float4*>(&vsh[wv][k0]);  // broadcast
                r = fmaf(bv.x, wt[(k0 + 0) * NF + lane], r);
                r = fmaf(bv.y, wt[(k0 + 1) * NF + lane], r);
                r = fmaf(bv.z, wt[(k0 + 2) * NF + lane], r);
                r = fmaf(bv.w, wt[(k0 + 3) * NF + lane], r);
            }
            out[(unsigned)d * NF + lane] = r;
        }
        g = gn; d = dn; ev = evn; mc = mcn;
    }
}

// ---------------- overflow fixup (post-GEMM, by linearity) ----------------
__global__ __launch_bounds__(64) void k_oflow(const float* __restrict__ x,
                                              const float* __restrict__ W,
                                              const int* __restrict__ degc,
                                              const int* __restrict__ ocnt,
                                              const int* __restrict__ oflow, int ocap,
                                              float* out) {
    int c = *ocnt; if (c > ocap) c = ocap;
    int lane = threadIdx.x;
    for (int o = blockIdx.x; o < c; o += gridDim.x) {
        int s = oflow[2 * o], d = oflow[2 * o + 1];
        float norm = rsqrtf((float)(degc[s] + 1)) * rsqrtf((float)(degc[d] + 1));
        float r = 0.f;
        for (int k = 0; k < NF; ++k)
            r = fmaf(x[(long)s * NF + k], W[lane * NF + k], r);
        atomicAdd(&out[(long)d * NF + lane], norm * r);
    }
}

// ---------------- launch ----------------

extern "C" void kernel_launch(void* const* d_in, const int* in_sizes, int n_in,
                              void* d_out, int out_size, void* d_ws, size_t ws_size,
                              hipStream_t stream) {
    const float* x    = (const float*)d_in[0];
    const int*   ei   = (const int*)d_in[1];   // harness pushes integers as int32
    const float* W    = (const float*)d_in[2];
    const float* bias = (const float*)d_in[3];
    float*       out  = (float*)d_out;

    const int n = in_sizes[0] / NF;       // 100000
    const int e = in_sizes[1] / 2;        // 1250000
    const int* src = ei;
    const int* dst = ei + e;

    // ws layout (runtime-sized): degc n | ocnt 1 | xs (n+1)*64 (256B-aligned) | oflow rest
    int*   degc = (int*)d_ws;
    int*   ocnt = degc + n;
    uintptr_t p = ((uintptr_t)(ocnt + 1) + 255) & ~(uintptr_t)255;
    float* xs   = (float*)p;
    int*   oflow = (int*)(xs + (size_t)(n + 1) * NF);
    long   rest = (long)ws_size - ((char*)oflow - (char*)d_ws);
    int    ocap = rest > 0 ? (int)(rest / 8) : 0;

    dim3 blk(256);
    hipMemsetAsync(degc, 0, (size_t)(n + 1) * sizeof(int), stream);  // degc + ocnt
    k_ell  <<<2048, blk, 0, stream>>>(src, dst, degc, ocnt, oflow, ocap, (int*)out, e, n);
    int total4 = (n + 1) * (NF / 4);
    k_scale<<<(total4 + 255) / 256, blk, 0, stream>>>(x, degc, xs, n);
    k_agg_gemm<<<2048, blk, 0, stream>>>(xs, W, bias, degc, out, n);
    k_oflow<<<64, 64, 0, stream>>>(x, W, degc, ocnt, oflow, ocap, out);
}

// Round 13
// 148.828 us; speedup vs baseline: 1.5341x; 1.0105x over previous
//
#include <hip/hip_runtime.h>
#include <hip/hip_fp16.h>
#include <stdint.h>

#define NF 64

// ---------------- single-pass ELL build (ELL inside d_out), XCD-windowed ----------------
__global__ __launch_bounds__(256) void k_ell(const int* __restrict__ src,
                                             const int* __restrict__ dst,
                                             int* degc, int* ocnt, int* oflow, int ocap,
                                             int* ell, int e, int n) {
    int grp = blockIdx.x & 7;
    int chunk = (n + 7) >> 3;
    int lo = grp * chunk;
    int hi = min(lo + chunk, n);
    int nb = gridDim.x >> 3;
    int bi = blockIdx.x >> 3;
    for (int i = bi * 256 + threadIdx.x; i < e; i += nb * 256) {
        int d = dst[i];
        if (d < lo || d >= hi) continue;
        int s = src[i];
        int slot = atomicAdd(&degc[d], 1);
        if (slot < NF) {
            ell[(unsigned)d * NF + slot] = s;
        } else {                                   // P(deg>64)~0; correctness fallback
            int o = atomicAdd(ocnt, 1);
            if (o < ocap) { oflow[2 * o] = s; oflow[2 * o + 1] = d; }
        }
    }
}

// ---------------- prescale to fp16: xh[row] = half(x[row] * rsqrt(deg+1)); row n = 0 ----------------
__global__ __launch_bounds__(256) void k_scale(const float* __restrict__ x,
                                               const int* __restrict__ degc,
                                               __half* __restrict__ xh, int n) {
    int i = blockIdx.x * 256 + threadIdx.x;      // float4 index (16 per row)
    int total = (n + 1) * (NF / 4);
    if (i >= total) return;
    int row = i >> 4;
    uint2 u = {0u, 0u};
    if (row < n) {
        float dd = rsqrtf((float)(degc[row] + 1));
        float4 v = reinterpret_cast<const float4*>(x)[i];
        __half2 p0 = __floats2half2_rn(v.x * dd, v.y * dd);
        __half2 p1 = __floats2half2_rn(v.z * dd, v.w * dd);
        u.x = *reinterpret_cast<unsigned*>(&p0);
        u.y = *reinterpret_cast<unsigned*>(&p1);
    }
    reinterpret_cast<uint2*>(xh)[i] = u;         // row n -> zero row
}

// ---------------- fused gather-aggregate + GEMM epilogue ----------------
// 1 node/wave, lane = feature. 16 gather chains (full ELL width per iter,
// deg<=16 -> single iteration, 16 rows in flight). fp16 rows = 2 lines each.
// Invalid slots -> L1-resident zero row n. No in-loop barriers.

__global__ __launch_bounds__(256) void k_agg_gemm(const __half* __restrict__ xh,
                                                  const float* __restrict__ W,
                                                  const float* __restrict__ bias,
                                                  const int* __restrict__ degc,
                                                  float* out, int n) {
    __shared__ float wt[NF * NF];      // wt[k*64+j] = W[j][k]
    __shared__ float vsh[4][NF];
    int tid = threadIdx.x;
    for (int idx = tid; idx < NF * NF; idx += 256) {
        int k = idx >> 6, j = idx & 63;
        wt[idx] = W[j * NF + k];
    }
    int wv = tid >> 6;
    unsigned lane = tid & 63;
    float bj = bias[lane];
    __syncthreads();                   // wt staged (only barrier)

    const int* outi = (const int*)out;   // ELL aliased in out
    int ngroups = (n + 3) >> 2, gs = gridDim.x;
    int g = blockIdx.x;
    int d = g * 4 + wv;
    int ev = 0, mc = 0;
    if (d < n) {
        ev = outi[(unsigned)d * NF + lane];    // full-wave 256B ELL row
        mc = degc[d];
    }
    while (g < ngroups) {
        int gn = g + gs, dn = gn * 4 + wv;
        int evn = 0, mcn = 0;
        if (gn < ngroups && dn < n) {          // prefetch next iteration
            evn = outi[(unsigned)dn * NF + lane];
            mcn = degc[dn];
        }
        if (d < n) {
            float dd = rsqrtf((float)(mc + 1));
            int m = min(mc, NF);
            float a0 = __half2float(xh[(unsigned)d * NF + lane]);   // self (prescaled)
            float a1 = 0.f, a2 = 0.f, a3 = 0.f, a4 = 0.f, a5 = 0.f, a6 = 0.f, a7 = 0.f;
            float a8 = 0.f, a9 = 0.f, a10 = 0.f, a11 = 0.f, a12 = 0.f, a13 = 0.f, a14 = 0.f, a15 = 0.f;
            for (int j = 0; j < m; j += 16) {  // 16 rows in flight, 1 ushort VMEM/edge
                int s0  = __shfl(ev, j + 0),  s1  = __shfl(ev, j + 1);
                int s2  = __shfl(ev, j + 2),  s3  = __shfl(ev, j + 3);
                int s4  = __shfl(ev, j + 4),  s5  = __shfl(ev, j + 5);
                int s6  = __shfl(ev, j + 6),  s7  = __shfl(ev, j + 7);
                int s8  = __shfl(ev, j + 8),  s9  = __shfl(ev, j + 9);
                int s10 = __shfl(ev, j + 10), s11 = __shfl(ev, j + 11);
                int s12 = __shfl(ev, j + 12), s13 = __shfl(ev, j + 13);
                int s14 = __shfl(ev, j + 14), s15 = __shfl(ev, j + 15);
                s0  = (j + 0  < m) ? s0  : n;  s1  = (j + 1  < m) ? s1  : n;
                s2  = (j + 2  < m) ? s2  : n;  s3  = (j + 3  < m) ? s3  : n;
                s4  = (j + 4  < m) ? s4  : n;  s5  = (j + 5  < m) ? s5  : n;
                s6  = (j + 6  < m) ? s6  : n;  s7  = (j + 7  < m) ? s7  : n;
                s8  = (j + 8  < m) ? s8  : n;  s9  = (j + 9  < m) ? s9  : n;
                s10 = (j + 10 < m) ? s10 : n;  s11 = (j + 11 < m) ? s11 : n;
                s12 = (j + 12 < m) ? s12 : n;  s13 = (j + 13 < m) ? s13 : n;
                s14 = (j + 14 < m) ? s14 : n;  s15 = (j + 15 < m) ? s15 : n;
                a0  += __half2float(xh[(unsigned)s0  * NF + lane]);
                a1  += __half2float(xh[(unsigned)s1  * NF + lane]);
                a2  += __half2float(xh[(unsigned)s2  * NF + lane]);
                a3  += __half2float(xh[(unsigned)s3  * NF + lane]);
                a4  += __half2float(xh[(unsigned)s4  * NF + lane]);
                a5  += __half2float(xh[(unsigned)s5  * NF + lane]);
                a6  += __half2float(xh[(unsigned)s6  * NF + lane]);
                a7  += __half2float(xh[(unsigned)s7  * NF + lane]);
                a8  += __half2float(xh[(unsigned)s8  * NF + lane]);
                a9  += __half2float(xh[(unsigned)s9  * NF + lane]);
                a10 += __half2float(xh[(unsigned)s10 * NF + lane]);
                a11 += __half2float(xh[(unsigned)s11 * NF + lane]);
                a12 += __half2float(xh[(unsigned)s12 * NF + lane]);
                a13 += __half2float(xh[(unsigned)s13 * NF + lane]);
                a14 += __half2float(xh[(unsigned)s14 * NF + lane]);
                a15 += __half2float(xh[(unsigned)s15 * NF + lane]);
            }
            float v = dd * ((((a0 + a1) + (a2 + a3)) + ((a4 + a5) + (a6 + a7)))
                          + (((a8 + a9) + (a10 + a11)) + ((a12 + a13) + (a14 + a15))));

            vsh[wv][lane] = v;                 // wave-local exchange, no barrier
            float r = bj;
#pragma unroll
            for (int k0 = 0; k0 < NF; k0 += 4) {
                float4 bv = *reinterpret_cast<const float4*>(&vsh[wv][k0]);  // broadcast
                r = fmaf(bv.x, wt[(k0 + 0) * NF + lane], r);
                r = fmaf(bv.y, wt[(k0 + 1) * NF + lane], r);
                r = fmaf(bv.z, wt[(k0 + 2) * NF + lane], r);
                r = fmaf(bv.w, wt[(k0 + 3) * NF + lane], r);
            }
            out[(unsigned)d * NF + lane] = r;
        }
        g = gn; d = dn; ev = evn; mc = mcn;
    }
}

// ---------------- overflow fixup (post-GEMM, by linearity; exact fp32 path) ----------------
__global__ __launch_bounds__(64) void k_oflow(const float* __restrict__ x,
                                              const float* __restrict__ W,
                                              const int* __restrict__ degc,
                                              const int* __restrict__ ocnt,
                                              const int* __restrict__ oflow, int ocap,
                                              float* out) {
    int c = *ocnt; if (c > ocap) c = ocap;
    int lane = threadIdx.x;
    for (int o = blockIdx.x; o < c; o += gridDim.x) {
        int s = oflow[2 * o], d = oflow[2 * o + 1];
        float norm = rsqrtf((float)(degc[s] + 1)) * rsqrtf((float)(degc[d] + 1));
        float r = 0.f;
        for (int k = 0; k < NF; ++k)
            r = fmaf(x[(long)s * NF + k], W[lane * NF + k], r);
        atomicAdd(&out[(long)d * NF + lane], norm * r);
    }
}

// ---------------- launch ----------------

extern "C" void kernel_launch(void* const* d_in, const int* in_sizes, int n_in,
                              void* d_out, int out_size, void* d_ws, size_t ws_size,
                              hipStream_t stream) {
    const float* x    = (const float*)d_in[0];
    const int*   ei   = (const int*)d_in[1];   // harness pushes integers as int32
    const float* W    = (const float*)d_in[2];
    const float* bias = (const float*)d_in[3];
    float*       out  = (float*)d_out;

    const int n = in_sizes[0] / NF;       // 100000
    const int e = in_sizes[1] / 2;        // 1250000
    const int* src = ei;
    const int* dst = ei + e;

    // ws layout: degc n | ocnt 1 | align | xh (n+1)*64 halfs | oflow rest
    int*    degc = (int*)d_ws;
    int*    ocnt = degc + n;
    uintptr_t p = ((uintptr_t)(ocnt + 1) + 255) & ~(uintptr_t)255;
    __half* xh   = (__half*)p;
    int*    oflow = (int*)(xh + (size_t)(n + 1) * NF);
    long    rest = (long)ws_size - ((char*)oflow - (char*)d_ws);
    int     ocap = rest > 0 ? (int)(rest / 8) : 0;

    dim3 blk(256);
    hipMemsetAsync(degc, 0, (size_t)(n + 1) * sizeof(int), stream);  // degc + ocnt
    k_ell  <<<2048, blk, 0, stream>>>(src, dst, degc, ocnt, oflow, ocap, (int*)out, e, n);
    int total4 = (n + 1) * (NF / 4);
    k_scale<<<(total4 + 255) / 256, blk, 0, stream>>>(x, degc, xh, n);
    k_agg_gemm<<<2048, blk, 0, stream>>>(xh, W, bias, degc, out, n);
    k_oflow<<<64, 64, 0, stream>>>(x, W, degc, ocnt, oflow, ocap, out);
}

// Round 14
// 145.982 us; speedup vs baseline: 1.5640x; 1.0195x over previous
//
#include <hip/hip_runtime.h>
#include <hip/hip_fp16.h>
#include <stdint.h>

#define NF 64

// ---------------- single-pass ELL build (ELL inside d_out), XCD-windowed ----------------
__global__ __launch_bounds__(256) void k_ell(const int* __restrict__ src,
                                             const int* __restrict__ dst,
                                             int* degc, int* ocnt, int* oflow, int ocap,
                                             int* ell, int e, int n) {
    int grp = blockIdx.x & 7;
    int chunk = (n + 7) >> 3;
    int lo = grp * chunk;
    int hi = min(lo + chunk, n);
    int nb = gridDim.x >> 3;
    int bi = blockIdx.x >> 3;
    for (int i = bi * 256 + threadIdx.x; i < e; i += nb * 256) {
        int d = dst[i];
        if (d < lo || d >= hi) continue;
        int s = src[i];
        int slot = atomicAdd(&degc[d], 1);
        if (slot < NF) {
            ell[(unsigned)d * NF + slot] = s;
        } else {                                   // P(deg>64)~0; correctness fallback
            int o = atomicAdd(ocnt, 1);
            if (o < ocap) { oflow[2 * o] = s; oflow[2 * o + 1] = d; }
        }
    }
}

// ---------------- prescale to fp16: xh[row] = half(x[row] * rsqrt(deg+1)); row n = 0 ----------------
__global__ __launch_bounds__(256) void k_scale(const float* __restrict__ x,
                                               const int* __restrict__ degc,
                                               __half* __restrict__ xh, int n) {
    int i = blockIdx.x * 256 + threadIdx.x;      // float4 index (16 per row)
    int total = (n + 1) * (NF / 4);
    if (i >= total) return;
    int row = i >> 4;
    uint2 u = {0u, 0u};
    if (row < n) {
        float dd = rsqrtf((float)(degc[row] + 1));
        float4 v = reinterpret_cast<const float4*>(x)[i];
        __half2 p0 = __floats2half2_rn(v.x * dd, v.y * dd);
        __half2 p1 = __floats2half2_rn(v.z * dd, v.w * dd);
        u.x = *reinterpret_cast<unsigned*>(&p0);
        u.y = *reinterpret_cast<unsigned*>(&p1);
    }
    reinterpret_cast<uint2*>(xh)[i] = u;         // row n -> zero row
}

// ---------------- fused gather-aggregate + GEMM epilogue ----------------
// 1 node/wave. Gather: 4 lane-groups x 16 lanes; group g takes edge j+g, lane
// loads uint2 (4 fp16 feats) -> ONE wave-load covers 4 edges' rows (4x fewer
// load instrs than lane-per-feature). f32 accumulation; groups combined via
// shfl_xor butterfly. Epilogue identical to R13. No in-loop barriers.

__global__ __launch_bounds__(256) void k_agg_gemm(const __half* __restrict__ xh,
                                                  const float* __restrict__ W,
                                                  const float* __restrict__ bias,
                                                  const int* __restrict__ degc,
                                                  float* out, int n) {
    __shared__ float wt[NF * NF];      // wt[k*64+j] = W[j][k]
    __shared__ float vsh[4][NF];
    int tid = threadIdx.x;
    for (int idx = tid; idx < NF * NF; idx += 256) {
        int k = idx >> 6, j = idx & 63;
        wt[idx] = W[j * NF + k];
    }
    int wv = tid >> 6;
    unsigned lane = tid & 63;
    unsigned grp = lane >> 4;          // 0..3: which edge of the quad
    unsigned fl  = lane & 15;          // feature-quad index: feats fl*4..fl*4+3
    float bj = bias[lane];
    __syncthreads();                   // wt staged (only barrier)

    const int* outi = (const int*)out;   // ELL aliased in out
    int ngroups = (n + 3) >> 2, gs = gridDim.x;
    int g = blockIdx.x;
    int d = g * 4 + wv;
    int ev = 0, mc = 0;
    if (d < n) {
        ev = outi[(unsigned)d * NF + lane];    // full-wave 256B ELL row
        mc = degc[d];
    }
    while (g < ngroups) {
        int gn = g + gs, dn = gn * 4 + wv;
        int evn = 0, mcn = 0;
        if (gn < ngroups && dn < n) {          // prefetch next iteration
            evn = outi[(unsigned)dn * NF + lane];
            mcn = degc[dn];
        }
        if (d < n) {
            float dd = rsqrtf((float)(mc + 1));
            int m = min(mc, NF);
            float a0 = 0.f, a1 = 0.f, a2 = 0.f, a3 = 0.f;   // chain A feats
            float b0 = 0.f, b1 = 0.f, b2 = 0.f, b3 = 0.f;   // chain B feats
            float c0 = 0.f, c1 = 0.f, c2 = 0.f, c3 = 0.f;   // chain C
            float e0 = 0.f, e1 = 0.f, e2 = 0.f, e3 = 0.f;   // chain D
            for (int j = 0; j < m; j += 16) {  // 16 edges = 4 wave-loads in flight
                int i0 = j + (int)grp, i1 = j + 4 + (int)grp;
                int i2 = j + 8 + (int)grp, i3 = j + 12 + (int)grp;
                int s0 = __shfl(ev, i0); s0 = (i0 < m) ? s0 : n;
                int s1 = __shfl(ev, i1); s1 = (i1 < m) ? s1 : n;
                int s2 = __shfl(ev, i2); s2 = (i2 < m) ? s2 : n;
                int s3 = __shfl(ev, i3); s3 = (i3 < m) ? s3 : n;
                uint2 u0 = *reinterpret_cast<const uint2*>(xh + (unsigned)s0 * NF + fl * 4);
                uint2 u1 = *reinterpret_cast<const uint2*>(xh + (unsigned)s1 * NF + fl * 4);
                uint2 u2 = *reinterpret_cast<const uint2*>(xh + (unsigned)s2 * NF + fl * 4);
                uint2 u3 = *reinterpret_cast<const uint2*>(xh + (unsigned)s3 * NF + fl * 4);
                float2 f;
                f = __half22float2(*reinterpret_cast<const __half2*>(&u0.x)); a0 += f.x; a1 += f.y;
                f = __half22float2(*reinterpret_cast<const __half2*>(&u0.y)); a2 += f.x; a3 += f.y;
                f = __half22float2(*reinterpret_cast<const __half2*>(&u1.x)); b0 += f.x; b1 += f.y;
                f = __half22float2(*reinterpret_cast<const __half2*>(&u1.y)); b2 += f.x; b3 += f.y;
                f = __half22float2(*reinterpret_cast<const __half2*>(&u2.x)); c0 += f.x; c1 += f.y;
                f = __half22float2(*reinterpret_cast<const __half2*>(&u2.y)); c2 += f.x; c3 += f.y;
                f = __half22float2(*reinterpret_cast<const __half2*>(&u3.x)); e0 += f.x; e1 += f.y;
                f = __half22float2(*reinterpret_cast<const __half2*>(&u3.y)); e2 += f.x; e3 += f.y;
            }
            // self term (prescaled row d), loaded per lane-group (broadcast within group)
            uint2 us = *reinterpret_cast<const uint2*>(xh + (unsigned)d * NF + fl * 4);
            float2 fs0 = __half22float2(*reinterpret_cast<const __half2*>(&us.x));
            float2 fs1 = __half22float2(*reinterpret_cast<const __half2*>(&us.y));
            a0 = (a0 + b0) + (c0 + e0);
            a1 = (a1 + b1) + (c1 + e1);
            a2 = (a2 + b2) + (c2 + e2);
            a3 = (a3 + b3) + (c3 + e3);
            // combine the 4 edge-groups: butterfly over lanes {fl, fl+16, fl+32, fl+48}
            a0 += __shfl_xor(a0, 16); a1 += __shfl_xor(a1, 16);
            a2 += __shfl_xor(a2, 16); a3 += __shfl_xor(a3, 16);
            a0 += __shfl_xor(a0, 32); a1 += __shfl_xor(a1, 32);
            a2 += __shfl_xor(a2, 32); a3 += __shfl_xor(a3, 32);
            if (grp == 0) {                     // lanes 0..15 write v as float4
                float4 v4;
                v4.x = dd * (a0 + fs0.x);
                v4.y = dd * (a1 + fs0.y);
                v4.z = dd * (a2 + fs1.x);
                v4.w = dd * (a3 + fs1.y);
                *reinterpret_cast<float4*>(&vsh[wv][fl * 4]) = v4;   // wave-local
            }
            float r = bj;
#pragma unroll
            for (int k0 = 0; k0 < NF; k0 += 4) {
                float4 bv = *reinterpret_cast<const float4*>(&vsh[wv][k0]);  // broadcast
                r = fmaf(bv.x, wt[(k0 + 0) * NF + lane], r);
                r = fmaf(bv.y, wt[(k0 + 1) * NF + lane], r);
                r = fmaf(bv.z, wt[(k0 + 2) * NF + lane], r);
                r = fmaf(bv.w, wt[(k0 + 3) * NF + lane], r);
            }
            out[(unsigned)d * NF + lane] = r;
        }
        g = gn; d = dn; ev = evn; mc = mcn;
    }
}

// ---------------- overflow fixup (post-GEMM, by linearity; exact fp32 path) ----------------
__global__ __launch_bounds__(64) void k_oflow(const float* __restrict__ x,
                                              const float* __restrict__ W,
                                              const int* __restrict__ degc,
                                              const int* __restrict__ ocnt,
                                              const int* __restrict__ oflow, int ocap,
                                              float* out) {
    int c = *ocnt; if (c > ocap) c = ocap;
    int lane = threadIdx.x;
    for (int o = blockIdx.x; o < c; o += gridDim.x) {
        int s = oflow[2 * o], d = oflow[2 * o + 1];
        float norm = rsqrtf((float)(degc[s] + 1)) * rsqrtf((float)(degc[d] + 1));
        float r = 0.f;
        for (int k = 0; k < NF; ++k)
            r = fmaf(x[(long)s * NF + k], W[lane * NF + k], r);
        atomicAdd(&out[(long)d * NF + lane], norm * r);
    }
}

// ---------------- launch ----------------

extern "C" void kernel_launch(void* const* d_in, const int* in_sizes, int n_in,
                              void* d_out, int out_size, void* d_ws, size_t ws_size,
                              hipStream_t stream) {
    const float* x    = (const float*)d_in[0];
    const int*   ei   = (const int*)d_in[1];   // harness pushes integers as int32
    const float* W    = (const float*)d_in[2];
    const float* bias = (const float*)d_in[3];
    float*       out  = (float*)d_out;

    const int n = in_sizes[0] / NF;       // 100000
    const int e = in_sizes[1] / 2;        // 1250000
    const int* src = ei;
    const int* dst = ei + e;

    // ws layout: degc n | ocnt 1 | align | xh (n+1)*64 halfs | oflow rest
    int*    degc = (int*)d_ws;
    int*    ocnt = degc + n;
    uintptr_t p = ((uintptr_t)(ocnt + 1) + 255) & ~(uintptr_t)255;
    __half* xh   = (__half*)p;
    int*    oflow = (int*)(xh + (size_t)(n + 1) * NF);
    long    rest = (long)ws_size - ((char*)oflow - (char*)d_ws);
    int     ocap = rest > 0 ? (int)(rest / 8) : 0;

    dim3 blk(256);
    hipMemsetAsync(degc, 0, (size_t)(n + 1) * sizeof(int), stream);  // degc + ocnt
    k_ell  <<<2048, blk, 0, stream>>>(src, dst, degc, ocnt, oflow, ocap, (int*)out, e, n);
    int total4 = (n + 1) * (NF / 4);
    k_scale<<<(total4 + 255) / 256, blk, 0, stream>>>(x, degc, xh, n);
    k_agg_gemm<<<2048, blk, 0, stream>>>(xh, W, bias, degc, out, n);
    k_oflow<<<64, 64, 0, stream>>>(x, W, degc, ocnt, oflow, ocap, out);
}